// Round 1
// baseline (334.567 us; speedup 1.0000x reference)
//
#include <hip/hip_runtime.h>

#define NHEADS 16
#define DIM 128
#define MQ 1024
#define LK 1024

#define K_BYTES 17408          // 64 rows x 136 ushort
#define V_BYTES 18432          // 128 rows x 72 ushort
#define TILE_BYTES 35840       // K_BYTES + V_BYTES (= 35 x 1024)
#define WS_NEED ((size_t)128 * 16 * TILE_BYTES)   // 73,400,320 B

typedef short short8 __attribute__((ext_vector_type(8)));
typedef float f32x16 __attribute__((ext_vector_type(16)));
typedef unsigned u32x4 __attribute__((ext_vector_type(4)));

// (1/sqrt(128)) * log2(e): fold softmax scale + exp2-domain into Q conversion
#define QSCALE_L2E 0.12751722f

// pack two floats -> two bf16 (round-to-nearest-even), self-contained
__device__ __forceinline__ unsigned pk2(float a, float b) {
  unsigned ua = __builtin_bit_cast(unsigned, a);
  unsigned ub = __builtin_bit_cast(unsigned, b);
  ua += 0x7fffu + ((ua >> 16) & 1u);
  ub += 0x7fffu + ((ub >> 16) & 1u);
  return (ua >> 16) | (ub & 0xffff0000u);
}
__device__ __forceinline__ short8 ld8(const unsigned short* p) {
  return __builtin_bit_cast(short8, *(const uint4*)p);
}

typedef const __attribute__((address_space(1))) void gvoid_t;
typedef __attribute__((address_space(3))) void lvoid_t;
__device__ __forceinline__ void gl_lds16(const void* g, void* l) {
  __builtin_amdgcn_global_load_lds((gvoid_t*)g, (lvoid_t*)l, 16, 0, 0);
}

// ---------------- prep kernel: fp32 K/V -> padded bf16 K-tile + transposed V-tile in ws ----
__global__ __launch_bounds__(256)
void SeqAttention_prep_kernel(const float* __restrict__ Kg,
                              const float* __restrict__ Vg,
                              const float* __restrict__ Sg,
                              unsigned char* __restrict__ ws) {
  const int bid = blockIdx.x;           // 2048 = 128 bh x 16 tiles
  const int bh = bid >> 4;
  const int it = bid & 15;
  const float sv = Sg[bh & (NHEADS - 1)];
  const float tval = 991.0f - sv * 1024.0f;
  int nf = (int)floorf(tval);
  nf = nf < 0 ? 0 : nf;
  if (it < (nf >> 6)) return;           // tile fully masked for this head -> never read

  const int tid = threadIdx.x;
  const int n0 = it << 6;
  unsigned char* dst = ws + (size_t)bid * TILE_BYTES;

  // ---- K: direct convert, rows stride 136 ushort ----
  {
    const int kn = tid >> 4;
    const int kc0 = (tid & 15) * 8;
    const float* Kb = Kg + (size_t)bh * LK * DIM;
    unsigned short* dk = (unsigned short*)dst;
#pragma unroll
    for (int p = 0; p < 4; ++p) {
      const int n = kn + p * 16;
      const float* kp = Kb + (size_t)(n0 + n) * DIM + kc0;
      float4 a = *(const float4*)kp;
      float4 bb = *(const float4*)(kp + 4);
      uint4 u;
      u.x = pk2(a.x, a.y); u.y = pk2(a.z, a.w);
      u.z = pk2(bb.x, bb.y); u.w = pk2(bb.z, bb.w);
      *(uint4*)&dk[n * 136 + kc0] = u;
    }
  }

  // ---- V: transpose via LDS, rows stride 72 ushort ----
  __shared__ __align__(16) unsigned short Vt[128 * 72];
  {
    const int vnp2 = (tid >> 3) * 2;
    const int vdq = (tid & 7) * 4;
    const float* Vb = Vg + (size_t)bh * LK * DIM;
#pragma unroll
    for (int p = 0; p < 4; ++p) {
      const int d0 = p * 32 + vdq;
      const float* vp = Vb + (size_t)(n0 + vnp2) * DIM + d0;
      float4 a = *(const float4*)vp;
      float4 bb = *(const float4*)(vp + DIM);
      *(unsigned*)&Vt[(d0 + 0) * 72 + vnp2] = pk2(a.x, bb.x);
      *(unsigned*)&Vt[(d0 + 1) * 72 + vnp2] = pk2(a.y, bb.y);
      *(unsigned*)&Vt[(d0 + 2) * 72 + vnp2] = pk2(a.z, bb.z);
      *(unsigned*)&Vt[(d0 + 3) * 72 + vnp2] = pk2(a.w, bb.w);
    }
  }
  __syncthreads();
  {
    const int d = tid >> 3;
    const int ch = tid & 7;
#pragma unroll
    for (int p = 0; p < 4; ++p) {
      const int dd = d + p * 32;
      *(uint4*)(dst + K_BYTES + dd * 144 + ch * 16) = *(const uint4*)&Vt[dd * 72 + ch * 8];
    }
  }
}

// ---------------- main kernel: 8-wave blocks (256 q-rows), double-buffered staging,
// ---------------- in-register P via permlane32_swap, 1 barrier/iter ----------
__global__ __launch_bounds__(512, 4)
void SeqAttention_59579786330678_kernel(const float* __restrict__ Qg,
                                        const unsigned char* __restrict__ ws,
                                        const float* __restrict__ Sg,
                                        float* __restrict__ Og) {
  // LDS: two staging buffers of TILE_BYTES each:
  //   buf[s]: Ks [64][136] bf16 at +0 (17408 B), Vt [128][72] bf16 at +17408 (18432 B)
  // epilogue reuses SM as float Otr[8][32][68] (69632 B)
  __shared__ __align__(16) unsigned char SM[2 * TILE_BYTES];

  const int tid = threadIdx.x;
  const int wid = tid >> 6;   // 0..7
  const int lane = tid & 63;
  const int lo = lane & 31;   // MFMA col -> this lane's query (within wave)
  const int hi = lane >> 5;   // MFMA k-half / row-offset bit

  // 512 blocks = 128 bh x 4 m-tiles (256 rows). Head-rotated so co-resident
  // blocks (stride 256 in dispatch order) carry different heads.
  const int bi = blockIdx.x;
  const int mt = bi >> 7;                    // 0..3
  const int h = ((bi & 15) + (mt << 2)) & 15;
  const int b = (bi >> 4) & 7;
  const int bh = b * NHEADS + h;
  const int m0 = mt << 8;

  const float sv = Sg[h];
  const float tval = 991.0f - sv * 1024.0f;
  int nf = (int)floorf(tval);
  nf = nf < 0 ? 0 : nf;
  const int tile0 = nf >> 6;

  // loop-invariant Q fragments (B-operand of K*Q^T), scale folded into bf16 convert
  short8 qf[8];
  {
    const float* qrow = Qg + ((size_t)bh * MQ + m0 + wid * 32 + lo) * DIM + hi * 8;
#pragma unroll
    for (int kc = 0; kc < 8; ++kc) {
      float4 x = *(const float4*)(qrow + kc * 16);
      float4 y = *(const float4*)(qrow + kc * 16 + 4);
      uint4 u;
      u.x = pk2(x.x * QSCALE_L2E, x.y * QSCALE_L2E);
      u.y = pk2(x.z * QSCALE_L2E, x.w * QSCALE_L2E);
      u.z = pk2(y.x * QSCALE_L2E, y.y * QSCALE_L2E);
      u.w = pk2(y.z * QSCALE_L2E, y.w * QSCALE_L2E);
      qf[kc] = __builtin_bit_cast(short8, u);
    }
  }

  f32x16 accO[4] = {};              // O^T accumulator: 4 d-blocks of 32
  float Mrun = -3.0e38f, lrun = 0.0f;
  const float hoff = (float)hi * 0.125f;   // 4*hi/32 row offset for mask

  const unsigned char* wsb = ws + (size_t)bh * 16 * TILE_BYTES;

  // ---- prologue: stage first tile into buf 0 ----
  {
    const unsigned char* src = wsb + (size_t)tile0 * TILE_BYTES;
    for (int c = wid; c < 35; c += 8)
      gl_lds16(src + c * 1024 + lane * 16, SM + c * 1024);
  }
  __syncthreads();   // drains vmcnt: buf0 ready

  int cur = 0;
  for (int it = tile0; it < 16; ++it) {
    // ---- issue next tile's staging EARLY into the other buffer (overlaps with compute) ----
    if (it + 1 < 16) {
      const unsigned char* src = wsb + (size_t)(it + 1) * TILE_BYTES;
      unsigned char* dstl = SM + (cur ^ 1) * TILE_BYTES;
      for (int c = wid; c < 35; c += 8)
        gl_lds16(src + c * 1024 + lane * 16, dstl + c * 1024);
    }

    unsigned short* Ksb = (unsigned short*)(SM + cur * TILE_BYTES);
    unsigned short* Vtb = Ksb + (K_BYTES / 2);
    const int n0 = it << 6;

    // ---- S^T = K * Q^T : rows n (0..63 in 2 blocks), cols m = lo ----
    f32x16 sa[2] = {};
    __builtin_amdgcn_s_setprio(1);
#pragma unroll
    for (int kc = 0; kc < 8; ++kc) {
      short8 k0 = ld8(&Ksb[lo * 136 + kc * 16 + hi * 8]);
      short8 k1 = ld8(&Ksb[(32 + lo) * 136 + kc * 16 + hi * 8]);
      sa[0] = __builtin_amdgcn_mfma_f32_32x32x16_bf16(k0, qf[kc], sa[0], 0, 0, 0);
      sa[1] = __builtin_amdgcn_mfma_f32_32x32x16_bf16(k1, qf[kc], sa[1], 0, 0, 0);
    }
    __builtin_amdgcn_s_setprio(0);

    // ---- online softmax over n for query m = lo (all in registers) ----
    float rm = -3.0e38f;
#pragma unroll
    for (int r = 0; r < 16; ++r) rm = fmaxf(rm, fmaxf(sa[0][r], sa[1][r]));
    rm = fmaxf(rm, __shfl_xor(rm, 32));
    const float Mn = fmaxf(Mrun, rm);
    const float alpha = __builtin_amdgcn_exp2f(Mrun - Mn);
    Mrun = Mn;

    const bool fullmask = ((float)n0 >= tval + 32.0f);  // whole tile has mask==1
    const float b0 = ((float)n0 - tval) * 0.03125f + hoff;
    float rs = 0.0f;
#pragma unroll
    for (int nb = 0; nb < 2; ++nb) {
#pragma unroll
      for (int g = 0; g < 4; ++g) {
#pragma unroll
        for (int i = 0; i < 4; ++i) {
          float e = __builtin_amdgcn_exp2f(sa[nb][g * 4 + i] - Mn);
          if (!fullmask) {
            float mv = b0 + (float)(i + 8 * g + 32 * nb) * 0.03125f;
            mv = __builtin_amdgcn_fmed3f(mv, 0.0f, 1.0f);
            e *= mv;
          }
          rs += e;
          sa[nb][g * 4 + i] = e;   // keep P in registers
        }
      }
    }
    rs += __shfl_xor(rs, 32);
    lrun = lrun * alpha + rs;
#pragma unroll
    for (int db = 0; db < 4; ++db)
#pragma unroll
      for (int r = 0; r < 16; ++r) accO[db][r] *= alpha;

    // ---- build PV B-fragments in-register: cvt_pk + permlane32_swap (no LDS round trip)
    // lane (lo,hi) holds P[m=lo][n = i + 8g + 4hi + 32nb]; B-frag pc needs
    // P[m=lo][n = pc*16 + hi*8 + j], j=0..7 -> exchange hi-halves once per dword pair.
    u32x4 pfv[4];
#pragma unroll
    for (int pc = 0; pc < 4; ++pc) {
      const int nb = pc >> 1;
      const int gX = (pc & 1) * 2;      // group needed by hi=0 destinations
      const int gY = gX + 1;            // group needed by hi=1 destinations
#pragma unroll
      for (int i0 = 0; i0 < 4; i0 += 2) {
        unsigned X = pk2(sa[nb][gX * 4 + i0], sa[nb][gX * 4 + i0 + 1]);
        unsigned Y = pk2(sa[nb][gY * 4 + i0], sa[nb][gY * 4 + i0 + 1]);
        // swaps X's upper 32 lanes with Y's lower 32 lanes:
        //   X'[l<32]=X[l], X'[l>=32]=Y[l-32]  -> dword (j = i0, i0+1)
        //   Y'[l<32]=X[l+32], Y'[l>=32]=Y[l]  -> dword (j = 4+i0, 5+i0)
        asm("v_permlane32_swap_b32 %0, %1" : "+v"(X), "+v"(Y));
        pfv[pc][i0 >> 1] = X;
        pfv[pc][2 + (i0 >> 1)] = Y;
      }
    }

    // ---- O^T += V^T * P^T ----
    __builtin_amdgcn_s_setprio(1);
#pragma unroll
    for (int pc = 0; pc < 4; ++pc) {
      short8 pf = __builtin_bit_cast(short8, pfv[pc]);
#pragma unroll
      for (int db = 0; db < 4; ++db) {
        short8 vf = ld8(&Vtb[(db * 32 + lo) * 72 + pc * 16 + hi * 8]);
        accO[db] = __builtin_amdgcn_mfma_f32_32x32x16_bf16(vf, pf, accO[db], 0, 0, 0);
      }
    }
    __builtin_amdgcn_s_setprio(0);

    // one barrier per iteration: drains my prefetch vmcnt (hidden under compute)
    // and guarantees everyone is done reading buf[cur] before it's re-staged.
    __syncthreads();
    cur ^= 1;
  }

  // ---- epilogue: /l, transpose O^T -> O via LDS (two d-halves), coalesced stores ----
  const float invl = 1.0f / lrun;
  float* Otr = (float*)SM + wid * (32 * 68);
  const size_t obase = ((size_t)bh * MQ + m0 + wid * 32) * DIM;
#pragma unroll
  for (int hf = 0; hf < 2; ++hf) {
    __syncthreads();
#pragma unroll
    for (int db = 0; db < 2; ++db) {
      const int adb = hf * 2 + db;
#pragma unroll
      for (int r = 0; r < 16; ++r) {
        const int dl = db * 32 + (r & 3) + 8 * (r >> 2) + 4 * hi;
        Otr[lo * 68 + dl] = accO[adb][r] * invl;
      }
    }
    __syncthreads();
    const int mr = lane >> 1;
    const int c0 = (lane & 1) * 32;
    const float* src2 = Otr + mr * 68 + c0;
    float* dst = Og + obase + (size_t)mr * DIM + hf * 64 + c0;
#pragma unroll
    for (int i = 0; i < 8; ++i)
      *(float4*)(dst + i * 4) = *(const float4*)(src2 + i * 4);
  }
}

// ---------------- fallback (small ws): inline-convert version, (256,3) ----------
__global__ __launch_bounds__(256, 3)
void SeqAttention_inline_kernel(const float* __restrict__ Qg,
                                const float* __restrict__ Kg,
                                const float* __restrict__ Vg,
                                const float* __restrict__ Sg,
                                float* __restrict__ Og) {
  __shared__ __align__(16) unsigned char SM[36864];
  unsigned short* Ks = (unsigned short*)SM;
  unsigned short* Pb = (unsigned short*)SM;
  unsigned short* Vt = (unsigned short*)(SM + 18432);

  const int tid = threadIdx.x;
  const int wid = tid >> 6;
  const int lane = tid & 63;
  const int lo = lane & 31;
  const int hi = lane >> 5;

  const int bi = blockIdx.x;
  const int q = bi >> 8;
  const int h = ((bi & 15) + (q << 2)) & 15;
  const int b = (bi >> 4) & 7;
  const int mt = (((bi >> 7) & 1) << 2) | q;
  const int bh = b * NHEADS + h;
  const int m0 = mt << 7;

  const float sv = Sg[h];
  const float tval = 991.0f - sv * 1024.0f;
  int nf = (int)floorf(tval);
  nf = nf < 0 ? 0 : nf;
  const int tile0 = nf >> 6;

  short8 qf[8];
  {
    const float* qrow = Qg + ((size_t)bh * MQ + m0 + wid * 32 + lo) * DIM + hi * 8;
#pragma unroll
    for (int kc = 0; kc < 8; ++kc) {
      float4 x = *(const float4*)(qrow + kc * 16);
      float4 y = *(const float4*)(qrow + kc * 16 + 4);
      uint4 u;
      u.x = pk2(x.x * QSCALE_L2E, x.y * QSCALE_L2E);
      u.y = pk2(x.z * QSCALE_L2E, x.w * QSCALE_L2E);
      u.z = pk2(y.x * QSCALE_L2E, y.y * QSCALE_L2E);
      u.w = pk2(y.z * QSCALE_L2E, y.w * QSCALE_L2E);
      qf[kc] = __builtin_bit_cast(short8, u);
    }
  }

  f32x16 accO[4] = {};
  float Mrun = -3.0e38f, lrun = 0.0f;
  const float hoff = (float)hi * 0.125f;

  const int vnp2 = (tid >> 3) * 2;
  const int vdq = (tid & 7) * 4;
  const int kn = tid >> 4;
  const int kc0 = (tid & 15) * 8;

  const float* Kbh = Kg + (size_t)bh * LK * DIM;
  const float* Vbh = Vg + (size_t)bh * LK * DIM;

  for (int it = tile0; it < 16; ++it) {
    const int n0 = it << 6;
#pragma unroll
    for (int p = 0; p < 4; ++p) {
      const int n = kn + p * 16;
      const float* kp = Kbh + (size_t)(n0 + n) * DIM + kc0;
      float4 a = *(const float4*)kp;
      float4 bb = *(const float4*)(kp + 4);
      uint4 u;
      u.x = pk2(a.x, a.y); u.y = pk2(a.z, a.w);
      u.z = pk2(bb.x, bb.y); u.w = pk2(bb.z, bb.w);
      *(uint4*)&Ks[n * 136 + kc0] = u;
    }
#pragma unroll
    for (int p = 0; p < 4; ++p) {
      const int d0 = p * 32 + vdq;
      const float* vp = Vbh + (size_t)(n0 + vnp2) * DIM + d0;
      float4 a = *(const float4*)vp;
      float4 bb = *(const float4*)(vp + DIM);
      *(unsigned*)&Vt[(d0 + 0) * 72 + vnp2] = pk2(a.x, bb.x);
      *(unsigned*)&Vt[(d0 + 1) * 72 + vnp2] = pk2(a.y, bb.y);
      *(unsigned*)&Vt[(d0 + 2) * 72 + vnp2] = pk2(a.z, bb.z);
      *(unsigned*)&Vt[(d0 + 3) * 72 + vnp2] = pk2(a.w, bb.w);
    }
    __syncthreads();

    f32x16 sa[2] = {};
#pragma unroll
    for (int kc = 0; kc < 8; ++kc) {
      short8 k0 = ld8(&Ks[lo * 136 + kc * 16 + hi * 8]);
      short8 k1 = ld8(&Ks[(32 + lo) * 136 + kc * 16 + hi * 8]);
      sa[0] = __builtin_amdgcn_mfma_f32_32x32x16_bf16(k0, qf[kc], sa[0], 0, 0, 0);
      sa[1] = __builtin_amdgcn_mfma_f32_32x32x16_bf16(k1, qf[kc], sa[1], 0, 0, 0);
    }
    __syncthreads();

    float rm = -3.0e38f;
#pragma unroll
    for (int r = 0; r < 16; ++r) rm = fmaxf(rm, fmaxf(sa[0][r], sa[1][r]));
    rm = fmaxf(rm, __shfl_xor(rm, 32));
    const float Mn = fmaxf(Mrun, rm);
    const float alpha = __builtin_amdgcn_exp2f(Mrun - Mn);
    Mrun = Mn;

    const bool fullmask = ((float)n0 >= tval + 32.0f);
    const float b0 = ((float)n0 - tval) * 0.03125f + hoff;
    unsigned short* pbrow = Pb + wid * (32 * 72) + lo * 72;
    float rs = 0.0f;
#pragma unroll
    for (int nb = 0; nb < 2; ++nb) {
#pragma unroll
      for (int g = 0; g < 4; ++g) {
        float pv0, pv1, pv2, pv3;
#pragma unroll
        for (int i = 0; i < 4; ++i) {
          float e = __builtin_amdgcn_exp2f(sa[nb][g * 4 + i] - Mn);
          if (!fullmask) {
            float mv = b0 + (float)(i + 8 * g + 32 * nb) * 0.03125f;
            mv = __builtin_amdgcn_fmed3f(mv, 0.0f, 1.0f);
            e *= mv;
          }
          rs += e;
          if (i == 0) pv0 = e; else if (i == 1) pv1 = e; else if (i == 2) pv2 = e; else pv3 = e;
        }
        uint2 w;
        w.x = pk2(pv0, pv1);
        w.y = pk2(pv2, pv3);
        *(uint2*)(pbrow + nb * 32 + g * 8 + hi * 4) = w;
      }
    }
    rs += __shfl_xor(rs, 32);
    lrun = lrun * alpha + rs;
#pragma unroll
    for (int db = 0; db < 4; ++db)
#pragma unroll
      for (int r = 0; r < 16; ++r) accO[db][r] *= alpha;

#pragma unroll
    for (int pc = 0; pc < 4; ++pc) {
      short8 pf = ld8(&Pb[wid * (32 * 72) + lo * 72 + pc * 16 + hi * 8]);
#pragma unroll
      for (int db = 0; db < 4; ++db) {
        short8 vf = ld8(&Vt[(db * 32 + lo) * 72 + pc * 16 + hi * 8]);
        accO[db] = __builtin_amdgcn_mfma_f32_32x32x16_bf16(vf, pf, accO[db], 0, 0, 0);
      }
    }
    __syncthreads();
  }

  const float invl = 1.0f / lrun;
  float* Otr = (float*)SM + wid * (32 * 68);
  const size_t obase = ((size_t)bh * MQ + m0 + wid * 32) * DIM;
#pragma unroll
  for (int hf = 0; hf < 2; ++hf) {
    __syncthreads();
#pragma unroll
    for (int db = 0; db < 2; ++db) {
      const int adb = hf * 2 + db;
#pragma unroll
      for (int r = 0; r < 16; ++r) {
        const int dl = db * 32 + (r & 3) + 8 * (r >> 2) + 4 * hi;
        Otr[lo * 68 + dl] = accO[adb][r] * invl;
      }
    }
    __syncthreads();
    const int mr = lane >> 1;
    const int c0 = (lane & 1) * 32;
    const float* src2 = Otr + mr * 68 + c0;
    float* dst = Og + obase + (size_t)mr * DIM + hf * 64 + c0;
#pragma unroll
    for (int i = 0; i < 8; ++i)
      *(float4*)(dst + i * 4) = *(const float4*)(src2 + i * 4);
  }
}

extern "C" void kernel_launch(void* const* d_in, const int* in_sizes, int n_in,
                              void* d_out, int out_size, void* d_ws, size_t ws_size,
                              hipStream_t stream) {
  const float* Q = (const float*)d_in[0];
  const float* K = (const float*)d_in[1];
  const float* V = (const float*)d_in[2];
  const float* S = (const float*)d_in[3];
  float* O = (float*)d_out;
  if (ws_size >= WS_NEED) {
    SeqAttention_prep_kernel<<<2048, 256, 0, stream>>>(K, V, S, (unsigned char*)d_ws);
    SeqAttention_59579786330678_kernel<<<512, 512, 0, stream>>>(
        Q, (const unsigned char*)d_ws, S, O);
  } else {
    SeqAttention_inline_kernel<<<1024, 256, 0, stream>>>(Q, K, V, S, O);
  }
}

// Round 2
// 302.550 us; speedup vs baseline: 1.1058x; 1.1058x over previous
//
#include <hip/hip_runtime.h>

#define NHEADS 16
#define DIM 128
#define MQ 1024
#define LK 1024

#define K_BYTES 17408          // 64 rows x 136 ushort
#define V_BYTES 18432          // 128 rows x 72 ushort
#define TILE_BYTES 35840       // K_BYTES + V_BYTES (= 35 x 1024)
#define WS_NEED ((size_t)128 * 16 * TILE_BYTES)   // 73,400,320 B

typedef short short8 __attribute__((ext_vector_type(8)));
typedef float f32x16 __attribute__((ext_vector_type(16)));
typedef unsigned u32x4 __attribute__((ext_vector_type(4)));

// (1/sqrt(128)) * log2(e): fold softmax scale + exp2-domain into Q conversion
#define QSCALE_L2E 0.12751722f

// pack two floats -> two bf16 (round-to-nearest-even), self-contained
__device__ __forceinline__ unsigned pk2(float a, float b) {
  unsigned ua = __builtin_bit_cast(unsigned, a);
  unsigned ub = __builtin_bit_cast(unsigned, b);
  ua += 0x7fffu + ((ua >> 16) & 1u);
  ub += 0x7fffu + ((ub >> 16) & 1u);
  return (ua >> 16) | (ub & 0xffff0000u);
}
__device__ __forceinline__ short8 ld8(const unsigned short* p) {
  return __builtin_bit_cast(short8, *(const uint4*)p);
}

typedef const __attribute__((address_space(1))) void gvoid_t;
typedef __attribute__((address_space(3))) void lvoid_t;
__device__ __forceinline__ void gl_lds16(const void* g, void* l) {
  __builtin_amdgcn_global_load_lds((gvoid_t*)g, (lvoid_t*)l, 16, 0, 0);
}

// ---------------- prep kernel: fp32 K/V -> padded bf16 K-tile + transposed V-tile in ws ----
__global__ __launch_bounds__(256)
void SeqAttention_prep_kernel(const float* __restrict__ Kg,
                              const float* __restrict__ Vg,
                              const float* __restrict__ Sg,
                              unsigned char* __restrict__ ws) {
  const int bid = blockIdx.x;           // 2048 = 128 bh x 16 tiles
  const int bh = bid >> 4;
  const int it = bid & 15;
  const float sv = Sg[bh & (NHEADS - 1)];
  const float tval = 991.0f - sv * 1024.0f;
  int nf = (int)floorf(tval);
  nf = nf < 0 ? 0 : nf;
  if (it < (nf >> 6)) return;           // tile fully masked for this head -> never read

  const int tid = threadIdx.x;
  const int n0 = it << 6;
  unsigned char* dst = ws + (size_t)bid * TILE_BYTES;

  // ---- K: direct convert, rows stride 136 ushort ----
  {
    const int kn = tid >> 4;
    const int kc0 = (tid & 15) * 8;
    const float* Kb = Kg + (size_t)bh * LK * DIM;
    unsigned short* dk = (unsigned short*)dst;
#pragma unroll
    for (int p = 0; p < 4; ++p) {
      const int n = kn + p * 16;
      const float* kp = Kb + (size_t)(n0 + n) * DIM + kc0;
      float4 a = *(const float4*)kp;
      float4 bb = *(const float4*)(kp + 4);
      uint4 u;
      u.x = pk2(a.x, a.y); u.y = pk2(a.z, a.w);
      u.z = pk2(bb.x, bb.y); u.w = pk2(bb.z, bb.w);
      *(uint4*)&dk[n * 136 + kc0] = u;
    }
  }

  // ---- V: transpose via LDS, rows stride 72 ushort ----
  __shared__ __align__(16) unsigned short Vt[128 * 72];
  {
    const int vnp2 = (tid >> 3) * 2;
    const int vdq = (tid & 7) * 4;
    const float* Vb = Vg + (size_t)bh * LK * DIM;
#pragma unroll
    for (int p = 0; p < 4; ++p) {
      const int d0 = p * 32 + vdq;
      const float* vp = Vb + (size_t)(n0 + vnp2) * DIM + d0;
      float4 a = *(const float4*)vp;
      float4 bb = *(const float4*)(vp + DIM);
      *(unsigned*)&Vt[(d0 + 0) * 72 + vnp2] = pk2(a.x, bb.x);
      *(unsigned*)&Vt[(d0 + 1) * 72 + vnp2] = pk2(a.y, bb.y);
      *(unsigned*)&Vt[(d0 + 2) * 72 + vnp2] = pk2(a.z, bb.z);
      *(unsigned*)&Vt[(d0 + 3) * 72 + vnp2] = pk2(a.w, bb.w);
    }
  }
  __syncthreads();
  {
    const int d = tid >> 3;
    const int ch = tid & 7;
#pragma unroll
    for (int p = 0; p < 4; ++p) {
      const int dd = d + p * 32;
      *(uint4*)(dst + K_BYTES + dd * 144 + ch * 16) = *(const uint4*)&Vt[dd * 72 + ch * 8];
    }
  }
}

// ---------------- main kernel: 4-wave blocks (128 q-rows), double-buffered staging,
// ---------------- in-register P via permlane32_swap, 1 barrier/iter, no spills ----------
__global__ __launch_bounds__(256, 2)
void SeqAttention_59579786330678_kernel(const float* __restrict__ Qg,
                                        const unsigned char* __restrict__ ws,
                                        const float* __restrict__ Sg,
                                        float* __restrict__ Og) {
  // LDS: two staging buffers of TILE_BYTES each:
  //   buf[s]: Ks [64][136] bf16 at +0 (17408 B), Vt [128][72] bf16 at +17408 (18432 B)
  // epilogue reuses SM as float Otr[4][32][68] (34816 B)
  __shared__ __align__(16) unsigned char SM[2 * TILE_BYTES];

  const int tid = threadIdx.x;
  const int wid = tid >> 6;   // 0..3
  const int lane = tid & 63;
  const int lo = lane & 31;   // MFMA col -> this lane's query (within wave)
  const int hi = lane >> 5;   // MFMA k-half / row-offset bit

  // Round-0 head-stratified swizzle: co-resident blocks (stride-256) get heads {x,x+4,x+8,x+12}
  const int bi = blockIdx.x;
  const int q = bi >> 8;
  const int h = ((bi & 15) + (q << 2)) & 15;
  const int b = (bi >> 4) & 7;
  const int mt = (((bi >> 7) & 1) << 2) | q;
  const int bh = b * NHEADS + h;
  const int m0 = mt << 7;

  const float sv = Sg[h];
  const float tval = 991.0f - sv * 1024.0f;
  int nf = (int)floorf(tval);
  nf = nf < 0 ? 0 : nf;
  const int tile0 = nf >> 6;

  // loop-invariant Q fragments (B-operand of K*Q^T), scale folded into bf16 convert
  short8 qf[8];
  {
    const float* qrow = Qg + ((size_t)bh * MQ + m0 + wid * 32 + lo) * DIM + hi * 8;
#pragma unroll
    for (int kc = 0; kc < 8; ++kc) {
      float4 x = *(const float4*)(qrow + kc * 16);
      float4 y = *(const float4*)(qrow + kc * 16 + 4);
      uint4 u;
      u.x = pk2(x.x * QSCALE_L2E, x.y * QSCALE_L2E);
      u.y = pk2(x.z * QSCALE_L2E, x.w * QSCALE_L2E);
      u.z = pk2(y.x * QSCALE_L2E, y.y * QSCALE_L2E);
      u.w = pk2(y.z * QSCALE_L2E, y.w * QSCALE_L2E);
      qf[kc] = __builtin_bit_cast(short8, u);
    }
  }

  f32x16 accO[4] = {};              // O^T accumulator: 4 d-blocks of 32
  float Mrun = -3.0e38f, lrun = 0.0f;
  const float hoff = (float)hi * 0.125f;   // 4*hi/32 row offset for mask

  const unsigned char* wsb = ws + (size_t)bh * 16 * TILE_BYTES;

  // ---- prologue: stage first tile into buf 0 ----
  {
    const unsigned char* src = wsb + (size_t)tile0 * TILE_BYTES;
    for (int c = wid; c < 35; c += 4)
      gl_lds16(src + c * 1024 + lane * 16, SM + c * 1024);
  }
  __syncthreads();   // drains vmcnt: buf0 ready

  int cur = 0;
  for (int it = tile0; it < 16; ++it) {
    // ---- issue next tile's staging EARLY into the other buffer (overlaps with compute) ----
    if (it + 1 < 16) {
      const unsigned char* src = wsb + (size_t)(it + 1) * TILE_BYTES;
      unsigned char* dstl = SM + (cur ^ 1) * TILE_BYTES;
      for (int c = wid; c < 35; c += 4)
        gl_lds16(src + c * 1024 + lane * 16, dstl + c * 1024);
    }

    unsigned short* Ksb = (unsigned short*)(SM + cur * TILE_BYTES);
    unsigned short* Vtb = Ksb + (K_BYTES / 2);
    const int n0 = it << 6;

    // ---- S^T = K * Q^T : rows n (0..63 in 2 blocks), cols m = lo ----
    f32x16 sa[2] = {};
    __builtin_amdgcn_s_setprio(1);
#pragma unroll
    for (int kc = 0; kc < 8; ++kc) {
      short8 k0 = ld8(&Ksb[lo * 136 + kc * 16 + hi * 8]);
      short8 k1 = ld8(&Ksb[(32 + lo) * 136 + kc * 16 + hi * 8]);
      sa[0] = __builtin_amdgcn_mfma_f32_32x32x16_bf16(k0, qf[kc], sa[0], 0, 0, 0);
      sa[1] = __builtin_amdgcn_mfma_f32_32x32x16_bf16(k1, qf[kc], sa[1], 0, 0, 0);
    }
    __builtin_amdgcn_s_setprio(0);

    // ---- online softmax over n for query m = lo (all in registers) ----
    float rm = -3.0e38f;
#pragma unroll
    for (int r = 0; r < 16; ++r) rm = fmaxf(rm, fmaxf(sa[0][r], sa[1][r]));
    rm = fmaxf(rm, __shfl_xor(rm, 32));
    const float Mn = fmaxf(Mrun, rm);
    const float alpha = __builtin_amdgcn_exp2f(Mrun - Mn);
    Mrun = Mn;

    const bool fullmask = ((float)n0 >= tval + 32.0f);  // whole tile has mask==1
    const float b0 = ((float)n0 - tval) * 0.03125f + hoff;
    float rs = 0.0f;
#pragma unroll
    for (int nb = 0; nb < 2; ++nb) {
#pragma unroll
      for (int g = 0; g < 4; ++g) {
#pragma unroll
        for (int i = 0; i < 4; ++i) {
          float e = __builtin_amdgcn_exp2f(sa[nb][g * 4 + i] - Mn);
          if (!fullmask) {
            float mv = b0 + (float)(i + 8 * g + 32 * nb) * 0.03125f;
            mv = __builtin_amdgcn_fmed3f(mv, 0.0f, 1.0f);
            e *= mv;
          }
          rs += e;
          sa[nb][g * 4 + i] = e;   // keep P in registers
        }
      }
    }
    rs += __shfl_xor(rs, 32);
    lrun = lrun * alpha + rs;
#pragma unroll
    for (int db = 0; db < 4; ++db)
#pragma unroll
      for (int r = 0; r < 16; ++r) accO[db][r] *= alpha;

    // ---- build PV B-fragments in-register: cvt_pk + permlane32_swap (no LDS round trip)
    // lane (lo,hi) holds P[m=lo][n = i + 8g + 4hi + 32nb]; B-frag pc needs
    // P[m=lo][n = pc*16 + hi*8 + j], j=0..7 -> exchange hi-halves once per dword pair.
    u32x4 pfv[4];
#pragma unroll
    for (int pc = 0; pc < 4; ++pc) {
      const int nb = pc >> 1;
      const int gX = (pc & 1) * 2;      // group needed by hi=0 destinations
      const int gY = gX + 1;            // group needed by hi=1 destinations
#pragma unroll
      for (int i0 = 0; i0 < 4; i0 += 2) {
        unsigned X = pk2(sa[nb][gX * 4 + i0], sa[nb][gX * 4 + i0 + 1]);
        unsigned Y = pk2(sa[nb][gY * 4 + i0], sa[nb][gY * 4 + i0 + 1]);
        // swaps X's upper 32 lanes with Y's lower 32 lanes:
        //   X'[l<32]=X[l], X'[l>=32]=Y[l-32]  -> dword (j = i0, i0+1)
        //   Y'[l<32]=X[l+32], Y'[l>=32]=Y[l]  -> dword (j = 4+i0, 5+i0)
        asm("v_permlane32_swap_b32 %0, %1" : "+v"(X), "+v"(Y));
        pfv[pc][i0 >> 1] = X;
        pfv[pc][2 + (i0 >> 1)] = Y;
      }
    }

    // ---- O^T += V^T * P^T ----
    __builtin_amdgcn_s_setprio(1);
#pragma unroll
    for (int pc = 0; pc < 4; ++pc) {
      short8 pf = __builtin_bit_cast(short8, pfv[pc]);
#pragma unroll
      for (int db = 0; db < 4; ++db) {
        short8 vf = ld8(&Vtb[(db * 32 + lo) * 72 + pc * 16 + hi * 8]);
        accO[db] = __builtin_amdgcn_mfma_f32_32x32x16_bf16(vf, pf, accO[db], 0, 0, 0);
      }
    }
    __builtin_amdgcn_s_setprio(0);

    // one barrier per iteration: drains my prefetch vmcnt (hidden under compute)
    // and guarantees everyone is done reading buf[cur] before it's re-staged.
    __syncthreads();
    cur ^= 1;
  }

  // ---- epilogue: /l, transpose O^T -> O via LDS (two d-halves), coalesced stores ----
  const float invl = 1.0f / lrun;
  float* Otr = (float*)SM + wid * (32 * 68);
  const size_t obase = ((size_t)bh * MQ + m0 + wid * 32) * DIM;
#pragma unroll
  for (int hf = 0; hf < 2; ++hf) {
    __syncthreads();
#pragma unroll
    for (int db = 0; db < 2; ++db) {
      const int adb = hf * 2 + db;
#pragma unroll
      for (int r = 0; r < 16; ++r) {
        const int dl = db * 32 + (r & 3) + 8 * (r >> 2) + 4 * hi;
        Otr[lo * 68 + dl] = accO[adb][r] * invl;
      }
    }
    __syncthreads();
    const int mr = lane >> 1;
    const int c0 = (lane & 1) * 32;
    const float* src2 = Otr + mr * 68 + c0;
    float* dst = Og + obase + (size_t)mr * DIM + hf * 64 + c0;
#pragma unroll
    for (int i = 0; i < 8; ++i)
      *(float4*)(dst + i * 4) = *(const float4*)(src2 + i * 4);
  }
}

// ---------------- fallback (small ws): inline-convert version, (256,3) ----------
__global__ __launch_bounds__(256, 3)
void SeqAttention_inline_kernel(const float* __restrict__ Qg,
                                const float* __restrict__ Kg,
                                const float* __restrict__ Vg,
                                const float* __restrict__ Sg,
                                float* __restrict__ Og) {
  __shared__ __align__(16) unsigned char SM[36864];
  unsigned short* Ks = (unsigned short*)SM;
  unsigned short* Pb = (unsigned short*)SM;
  unsigned short* Vt = (unsigned short*)(SM + 18432);

  const int tid = threadIdx.x;
  const int wid = tid >> 6;
  const int lane = tid & 63;
  const int lo = lane & 31;
  const int hi = lane >> 5;

  const int bi = blockIdx.x;
  const int q = bi >> 8;
  const int h = ((bi & 15) + (q << 2)) & 15;
  const int b = (bi >> 4) & 7;
  const int mt = (((bi >> 7) & 1) << 2) | q;
  const int bh = b * NHEADS + h;
  const int m0 = mt << 7;

  const float sv = Sg[h];
  const float tval = 991.0f - sv * 1024.0f;
  int nf = (int)floorf(tval);
  nf = nf < 0 ? 0 : nf;
  const int tile0 = nf >> 6;

  short8 qf[8];
  {
    const float* qrow = Qg + ((size_t)bh * MQ + m0 + wid * 32 + lo) * DIM + hi * 8;
#pragma unroll
    for (int kc = 0; kc < 8; ++kc) {
      float4 x = *(const float4*)(qrow + kc * 16);
      float4 y = *(const float4*)(qrow + kc * 16 + 4);
      uint4 u;
      u.x = pk2(x.x * QSCALE_L2E, x.y * QSCALE_L2E);
      u.y = pk2(x.z * QSCALE_L2E, x.w * QSCALE_L2E);
      u.z = pk2(y.x * QSCALE_L2E, y.y * QSCALE_L2E);
      u.w = pk2(y.z * QSCALE_L2E, y.w * QSCALE_L2E);
      qf[kc] = __builtin_bit_cast(short8, u);
    }
  }

  f32x16 accO[4] = {};
  float Mrun = -3.0e38f, lrun = 0.0f;
  const float hoff = (float)hi * 0.125f;

  const int vnp2 = (tid >> 3) * 2;
  const int vdq = (tid & 7) * 4;
  const int kn = tid >> 4;
  const int kc0 = (tid & 15) * 8;

  const float* Kbh = Kg + (size_t)bh * LK * DIM;
  const float* Vbh = Vg + (size_t)bh * LK * DIM;

  for (int it = tile0; it < 16; ++it) {
    const int n0 = it << 6;
#pragma unroll
    for (int p = 0; p < 4; ++p) {
      const int n = kn + p * 16;
      const float* kp = Kbh + (size_t)(n0 + n) * DIM + kc0;
      float4 a = *(const float4*)kp;
      float4 bb = *(const float4*)(kp + 4);
      uint4 u;
      u.x = pk2(a.x, a.y); u.y = pk2(a.z, a.w);
      u.z = pk2(bb.x, bb.y); u.w = pk2(bb.z, bb.w);
      *(uint4*)&Ks[n * 136 + kc0] = u;
    }
#pragma unroll
    for (int p = 0; p < 4; ++p) {
      const int d0 = p * 32 + vdq;
      const float* vp = Vbh + (size_t)(n0 + vnp2) * DIM + d0;
      float4 a = *(const float4*)vp;
      float4 bb = *(const float4*)(vp + DIM);
      *(unsigned*)&Vt[(d0 + 0) * 72 + vnp2] = pk2(a.x, bb.x);
      *(unsigned*)&Vt[(d0 + 1) * 72 + vnp2] = pk2(a.y, bb.y);
      *(unsigned*)&Vt[(d0 + 2) * 72 + vnp2] = pk2(a.z, bb.z);
      *(unsigned*)&Vt[(d0 + 3) * 72 + vnp2] = pk2(a.w, bb.w);
    }
    __syncthreads();

    f32x16 sa[2] = {};
#pragma unroll
    for (int kc = 0; kc < 8; ++kc) {
      short8 k0 = ld8(&Ks[lo * 136 + kc * 16 + hi * 8]);
      short8 k1 = ld8(&Ks[(32 + lo) * 136 + kc * 16 + hi * 8]);
      sa[0] = __builtin_amdgcn_mfma_f32_32x32x16_bf16(k0, qf[kc], sa[0], 0, 0, 0);
      sa[1] = __builtin_amdgcn_mfma_f32_32x32x16_bf16(k1, qf[kc], sa[1], 0, 0, 0);
    }
    __syncthreads();

    float rm = -3.0e38f;
#pragma unroll
    for (int r = 0; r < 16; ++r) rm = fmaxf(rm, fmaxf(sa[0][r], sa[1][r]));
    rm = fmaxf(rm, __shfl_xor(rm, 32));
    const float Mn = fmaxf(Mrun, rm);
    const float alpha = __builtin_amdgcn_exp2f(Mrun - Mn);
    Mrun = Mn;

    const bool fullmask = ((float)n0 >= tval + 32.0f);
    const float b0 = ((float)n0 - tval) * 0.03125f + hoff;
    unsigned short* pbrow = Pb + wid * (32 * 72) + lo * 72;
    float rs = 0.0f;
#pragma unroll
    for (int nb = 0; nb < 2; ++nb) {
#pragma unroll
      for (int g = 0; g < 4; ++g) {
        float pv0, pv1, pv2, pv3;
#pragma unroll
        for (int i = 0; i < 4; ++i) {
          float e = __builtin_amdgcn_exp2f(sa[nb][g * 4 + i] - Mn);
          if (!fullmask) {
            float mv = b0 + (float)(i + 8 * g + 32 * nb) * 0.03125f;
            mv = __builtin_amdgcn_fmed3f(mv, 0.0f, 1.0f);
            e *= mv;
          }
          rs += e;
          if (i == 0) pv0 = e; else if (i == 1) pv1 = e; else if (i == 2) pv2 = e; else pv3 = e;
        }
        uint2 w;
        w.x = pk2(pv0, pv1);
        w.y = pk2(pv2, pv3);
        *(uint2*)(pbrow + nb * 32 + g * 8 + hi * 4) = w;
      }
    }
    rs += __shfl_xor(rs, 32);
    lrun = lrun * alpha + rs;
#pragma unroll
    for (int db = 0; db < 4; ++db)
#pragma unroll
      for (int r = 0; r < 16; ++r) accO[db][r] *= alpha;

#pragma unroll
    for (int pc = 0; pc < 4; ++pc) {
      short8 pf = ld8(&Pb[wid * (32 * 72) + lo * 72 + pc * 16 + hi * 8]);
#pragma unroll
      for (int db = 0; db < 4; ++db) {
        short8 vf = ld8(&Vt[(db * 32 + lo) * 72 + pc * 16 + hi * 8]);
        accO[db] = __builtin_amdgcn_mfma_f32_32x32x16_bf16(vf, pf, accO[db], 0, 0, 0);
      }
    }
    __syncthreads();
  }

  const float invl = 1.0f / lrun;
  float* Otr = (float*)SM + wid * (32 * 68);
  const size_t obase = ((size_t)bh * MQ + m0 + wid * 32) * DIM;
#pragma unroll
  for (int hf = 0; hf < 2; ++hf) {
    __syncthreads();
#pragma unroll
    for (int db = 0; db < 2; ++db) {
      const int adb = hf * 2 + db;
#pragma unroll
      for (int r = 0; r < 16; ++r) {
        const int dl = db * 32 + (r & 3) + 8 * (r >> 2) + 4 * hi;
        Otr[lo * 68 + dl] = accO[adb][r] * invl;
      }
    }
    __syncthreads();
    const int mr = lane >> 1;
    const int c0 = (lane & 1) * 32;
    const float* src2 = Otr + mr * 68 + c0;
    float* dst = Og + obase + (size_t)mr * DIM + hf * 64 + c0;
#pragma unroll
    for (int i = 0; i < 8; ++i)
      *(float4*)(dst + i * 4) = *(const float4*)(src2 + i * 4);
  }
}

extern "C" void kernel_launch(void* const* d_in, const int* in_sizes, int n_in,
                              void* d_out, int out_size, void* d_ws, size_t ws_size,
                              hipStream_t stream) {
  const float* Q = (const float*)d_in[0];
  const float* K = (const float*)d_in[1];
  const float* V = (const float*)d_in[2];
  const float* S = (const float*)d_in[3];
  float* O = (float*)d_out;
  if (ws_size >= WS_NEED) {
    SeqAttention_prep_kernel<<<2048, 256, 0, stream>>>(K, V, S, (unsigned char*)d_ws);
    SeqAttention_59579786330678_kernel<<<1024, 256, 0, stream>>>(
        Q, (const unsigned char*)d_ws, S, O);
  } else {
    SeqAttention_inline_kernel<<<1024, 256, 0, stream>>>(Q, K, V, S, O);
  }
}

// Round 3
// 285.869 us; speedup vs baseline: 1.1704x; 1.0584x over previous
//
#include <hip/hip_runtime.h>

#define NHEADS 16
#define DIM 128
#define MQ 1024
#define LK 1024

#define K_BYTES 16384          // 64 rows x 128 ushort, 16B-chunk XOR-swizzled
#define V_BYTES 16384          // 128 rows x 64 ushort, 16B-chunk XOR-swizzled
#define TILE_BYTES 32768       // K_BYTES + V_BYTES
#define WS_NEED ((size_t)128 * 16 * TILE_BYTES)   // 67,108,864 B

typedef short short8 __attribute__((ext_vector_type(8)));
typedef float f32x16 __attribute__((ext_vector_type(16)));
typedef unsigned u32x4 __attribute__((ext_vector_type(4)));

// (1/sqrt(128)) * log2(e): fold softmax scale + exp2-domain into Q conversion
#define QSCALE_L2E 0.12751722f

// pack two floats -> two bf16 (round-to-nearest-even), self-contained
__device__ __forceinline__ unsigned pk2(float a, float b) {
  unsigned ua = __builtin_bit_cast(unsigned, a);
  unsigned ub = __builtin_bit_cast(unsigned, b);
  ua += 0x7fffu + ((ua >> 16) & 1u);
  ub += 0x7fffu + ((ub >> 16) & 1u);
  return (ua >> 16) | (ub & 0xffff0000u);
}
__device__ __forceinline__ short8 ld8(const unsigned short* p) {
  return __builtin_bit_cast(short8, *(const uint4*)p);
}

typedef const __attribute__((address_space(1))) void gvoid_t;
typedef __attribute__((address_space(3))) void lvoid_t;
__device__ __forceinline__ void gl_lds16(const void* g, void* l) {
  __builtin_amdgcn_global_load_lds((gvoid_t*)g, (lvoid_t*)l, 16, 0, 0);
}

// ---------------- prep kernel: fp32 K/V -> swizzled bf16 K-tile + transposed V-tile in ws ----
// Layout (per tile): K rows stride 128 ushort, 16B chunk index XOR'd with (row&7);
//                    V^T rows stride 64 ushort, same chunk swizzle.
// Main kernel stages these linearly into LDS and applies the same XOR on reads
// (both-sides involution, G21) -> bank-conflict-free without padding.
__global__ __launch_bounds__(256)
void SeqAttention_prep_kernel(const float* __restrict__ Kg,
                              const float* __restrict__ Vg,
                              const float* __restrict__ Sg,
                              unsigned char* __restrict__ ws) {
  const int bid = blockIdx.x;           // 2048 = 128 bh x 16 tiles
  const int bh = bid >> 4;
  const int it = bid & 15;
  const float sv = Sg[bh & (NHEADS - 1)];
  const float tval = 991.0f - sv * 1024.0f;
  int nf = (int)floorf(tval);
  nf = nf < 0 ? 0 : nf;
  if (it < (nf >> 6)) return;           // tile fully masked for this head -> never read

  const int tid = threadIdx.x;
  const int n0 = it << 6;
  unsigned char* dst = ws + (size_t)bid * TILE_BYTES;

  // ---- K: direct convert, swizzled chunk placement ----
  {
    const int kn = tid >> 4;
    const int kc0 = (tid & 15) * 8;     // ushort col, multiple of 8 (one 16B chunk)
    const float* Kb = Kg + (size_t)bh * LK * DIM;
    unsigned short* dk = (unsigned short*)dst;
#pragma unroll
    for (int p = 0; p < 4; ++p) {
      const int n = kn + p * 16;
      const float* kp = Kb + (size_t)(n0 + n) * DIM + kc0;
      float4 a = *(const float4*)kp;
      float4 bb = *(const float4*)(kp + 4);
      uint4 u;
      u.x = pk2(a.x, a.y); u.y = pk2(a.z, a.w);
      u.z = pk2(bb.x, bb.y); u.w = pk2(bb.z, bb.w);
      *(uint4*)&dk[n * 128 + (kc0 ^ ((n & 7) << 3))] = u;
    }
  }

  // ---- V: transpose via LDS (padded stride 72 internally), swizzled copy-out ----
  __shared__ __align__(16) unsigned short Vt[128 * 72];
  {
    const int vnp2 = (tid >> 3) * 2;
    const int vdq = (tid & 7) * 4;
    const float* Vb = Vg + (size_t)bh * LK * DIM;
#pragma unroll
    for (int p = 0; p < 4; ++p) {
      const int d0 = p * 32 + vdq;
      const float* vp = Vb + (size_t)(n0 + vnp2) * DIM + d0;
      float4 a = *(const float4*)vp;
      float4 bb = *(const float4*)(vp + DIM);
      *(unsigned*)&Vt[(d0 + 0) * 72 + vnp2] = pk2(a.x, bb.x);
      *(unsigned*)&Vt[(d0 + 1) * 72 + vnp2] = pk2(a.y, bb.y);
      *(unsigned*)&Vt[(d0 + 2) * 72 + vnp2] = pk2(a.z, bb.z);
      *(unsigned*)&Vt[(d0 + 3) * 72 + vnp2] = pk2(a.w, bb.w);
    }
  }
  __syncthreads();
  {
    const int d = tid >> 3;
    const int ch = tid & 7;
#pragma unroll
    for (int p = 0; p < 4; ++p) {
      const int dd = d + p * 32;
      *(uint4*)(dst + K_BYTES + dd * 128 + ((ch * 16) ^ ((dd & 7) << 4))) =
          *(const uint4*)&Vt[dd * 72 + ch * 8];
    }
  }
}

// ---------------- main kernel: 4-wave blocks, K double-buffered + V single-buffered,
// ---------------- counted vmcnt waits, in-register P, 48 KB LDS -> 3 blocks/CU ----------
__global__ __launch_bounds__(256, 3)
void SeqAttention_59579786330678_kernel(const float* __restrict__ Qg,
                                        const unsigned char* __restrict__ ws,
                                        const float* __restrict__ Sg,
                                        float* __restrict__ Og) {
  // LDS: Kbuf0 @0 (16K), Kbuf1 @16K, Vbuf @32K (16K). Total 48K -> 3 blocks/CU.
  // epilogue reuses SM as float Otr[4][32][68] (34816 B)
  __shared__ __align__(16) unsigned char SM[49152];

  const int tid = threadIdx.x;
  const int wid = tid >> 6;   // 0..3
  const int lane = tid & 63;
  const int lo = lane & 31;   // MFMA col -> this lane's query (within wave)
  const int hi = lane >> 5;   // MFMA k-half / row-offset bit
  const int xk = (lo & 7) << 3;   // ushort-index XOR for swizzled LDS reads

  // Head-stratified swizzle: co-resident blocks (stride-256) get heads {x,x+4,x+8,x+12}
  const int bi = blockIdx.x;
  const int q = bi >> 8;
  const int h = ((bi & 15) + (q << 2)) & 15;
  const int b = (bi >> 4) & 7;
  const int mt = (((bi >> 7) & 1) << 2) | q;
  const int bh = b * NHEADS + h;
  const int m0 = mt << 7;

  const float sv = Sg[h];
  const float tval = 991.0f - sv * 1024.0f;
  int nf = (int)floorf(tval);
  nf = nf < 0 ? 0 : nf;
  const int tile0 = nf >> 6;

  // loop-invariant Q fragments (B-operand of K*Q^T), scale folded into bf16 convert
  short8 qf[8];
  {
    const float* qrow = Qg + ((size_t)bh * MQ + m0 + wid * 32 + lo) * DIM + hi * 8;
#pragma unroll
    for (int kc = 0; kc < 8; ++kc) {
      float4 x = *(const float4*)(qrow + kc * 16);
      float4 y = *(const float4*)(qrow + kc * 16 + 4);
      uint4 u;
      u.x = pk2(x.x * QSCALE_L2E, x.y * QSCALE_L2E);
      u.y = pk2(x.z * QSCALE_L2E, x.w * QSCALE_L2E);
      u.z = pk2(y.x * QSCALE_L2E, y.y * QSCALE_L2E);
      u.w = pk2(y.z * QSCALE_L2E, y.w * QSCALE_L2E);
      qf[kc] = __builtin_bit_cast(short8, u);
    }
  }

  f32x16 accO[4] = {};              // O^T accumulator: 4 d-blocks of 32
  float Mrun = -3.0e38f, lrun = 0.0f;
  const float hoff = (float)hi * 0.125f;   // 4*hi/32 row offset for mask

  const unsigned char* wsb = ws + (size_t)bh * 16 * TILE_BYTES;

  // ---- prologue: stage K(tile0) into Kbuf0 ----
  {
    const unsigned char* src = wsb + (size_t)tile0 * TILE_BYTES;
    for (int c = wid; c < 16; c += 4)
      gl_lds16(src + c * 1024 + lane * 16, SM + c * 1024);
  }
  __syncthreads();   // drains vmcnt: Kbuf0 ready

  int cur = 0;
  for (int it = tile0; it < 16; ++it) {
    // ---- issue V(it) stage (waited at pre-PV barrier, hidden under QK^T+softmax) ----
    {
      const unsigned char* src = wsb + (size_t)it * TILE_BYTES + K_BYTES;
      for (int c = wid; c < 16; c += 4)
        gl_lds16(src + c * 1024 + lane * 16, SM + 32768 + c * 1024);
    }
    // ---- issue K(it+1) prefetch (drained at end-of-iter syncthreads) ----
    if (it + 1 < 16) {
      const unsigned char* srcn = wsb + (size_t)(it + 1) * TILE_BYTES;
      unsigned char* dstl = SM + (cur ^ 1) * K_BYTES;
      for (int c = wid; c < 16; c += 4)
        gl_lds16(srcn + c * 1024 + lane * 16, dstl + c * 1024);
    }

    const unsigned short* Ksb = (const unsigned short*)(SM + cur * K_BYTES);
    const unsigned short* Vtb = (const unsigned short*)(SM + 32768);
    const int n0 = it << 6;

    // ---- S^T = K * Q^T : rows n (0..63 in 2 blocks), cols m = lo ----
    f32x16 sa[2] = {};
    __builtin_amdgcn_s_setprio(1);
#pragma unroll
    for (int kc = 0; kc < 8; ++kc) {
      short8 k0 = ld8(&Ksb[lo * 128 + ((kc * 16 + hi * 8) ^ xk)]);
      short8 k1 = ld8(&Ksb[(32 + lo) * 128 + ((kc * 16 + hi * 8) ^ xk)]);
      sa[0] = __builtin_amdgcn_mfma_f32_32x32x16_bf16(k0, qf[kc], sa[0], 0, 0, 0);
      sa[1] = __builtin_amdgcn_mfma_f32_32x32x16_bf16(k1, qf[kc], sa[1], 0, 0, 0);
    }
    __builtin_amdgcn_s_setprio(0);

    // ---- online softmax (registers only), T13 defer-max: skip rescale when
    // ---- tile max grew < 8 (exp2 domain) -> P bounded by 2^8, bf16-safe ----
    float rm = -3.0e38f;
#pragma unroll
    for (int r = 0; r < 16; ++r) rm = fmaxf(rm, fmaxf(sa[0][r], sa[1][r]));
    rm = fmaxf(rm, __shfl_xor(rm, 32));
    if (!__all(rm <= Mrun + 8.0f)) {
      const float Mn = fmaxf(Mrun, rm);
      const float alpha = __builtin_amdgcn_exp2f(Mrun - Mn);
      lrun *= alpha;
#pragma unroll
      for (int db = 0; db < 4; ++db)
#pragma unroll
        for (int r = 0; r < 16; ++r) accO[db][r] *= alpha;
      Mrun = Mn;
    }

    const bool fullmask = ((float)n0 >= tval + 32.0f);  // whole tile has mask==1
    const float b0 = ((float)n0 - tval) * 0.03125f + hoff;
    float rs = 0.0f;
#pragma unroll
    for (int nb = 0; nb < 2; ++nb) {
#pragma unroll
      for (int g = 0; g < 4; ++g) {
#pragma unroll
        for (int i = 0; i < 4; ++i) {
          float e = __builtin_amdgcn_exp2f(sa[nb][g * 4 + i] - Mrun);
          if (!fullmask) {
            float mv = b0 + (float)(i + 8 * g + 32 * nb) * 0.03125f;
            mv = __builtin_amdgcn_fmed3f(mv, 0.0f, 1.0f);
            e *= mv;
          }
          rs += e;
          sa[nb][g * 4 + i] = e;   // keep P in registers
        }
      }
    }
    rs += __shfl_xor(rs, 32);
    lrun += rs;

    // ---- build PV B-fragments in-register: cvt_pk + permlane32_swap ----
    u32x4 pfv[4];
#pragma unroll
    for (int pc = 0; pc < 4; ++pc) {
      const int nb = pc >> 1;
      const int gX = (pc & 1) * 2;      // group needed by hi=0 destinations
      const int gY = gX + 1;            // group needed by hi=1 destinations
#pragma unroll
      for (int i0 = 0; i0 < 4; i0 += 2) {
        unsigned X = pk2(sa[nb][gX * 4 + i0], sa[nb][gX * 4 + i0 + 1]);
        unsigned Y = pk2(sa[nb][gY * 4 + i0], sa[nb][gY * 4 + i0 + 1]);
        asm("v_permlane32_swap_b32 %0, %1" : "+v"(X), "+v"(Y));
        pfv[pc][i0 >> 1] = X;
        pfv[pc][2 + (i0 >> 1)] = Y;
      }
    }

    // ---- wait V(it) staged (counted: leave the 4 K-prefetch loads in flight) ----
    if (it + 1 < 16) {
      asm volatile("s_waitcnt vmcnt(4)" ::: "memory");
    } else {
      asm volatile("s_waitcnt vmcnt(0)" ::: "memory");
    }
    __builtin_amdgcn_s_barrier();
    __builtin_amdgcn_sched_barrier(0);   // keep Vtb reads below the barrier

    // ---- O^T += V^T * P^T ----
    __builtin_amdgcn_s_setprio(1);
#pragma unroll
    for (int pc = 0; pc < 4; ++pc) {
      short8 pf = __builtin_bit_cast(short8, pfv[pc]);
#pragma unroll
      for (int db = 0; db < 4; ++db) {
        short8 vf = ld8(&Vtb[(db * 32 + lo) * 64 + ((pc * 16 + hi * 8) ^ xk)]);
        accO[db] = __builtin_amdgcn_mfma_f32_32x32x16_bf16(vf, pf, accO[db], 0, 0, 0);
      }
    }
    __builtin_amdgcn_s_setprio(0);

    // end barrier: drains K(it+1) prefetch (hidden under this whole iteration),
    // protects Vbuf and Kbuf[cur] for next iteration's staging.
    __syncthreads();
    cur ^= 1;
  }

  // ---- epilogue: /l, transpose O^T -> O via LDS (two d-halves), coalesced stores ----
  const float invl = 1.0f / lrun;
  float* Otr = (float*)SM + wid * (32 * 68);
  const size_t obase = ((size_t)bh * MQ + m0 + wid * 32) * DIM;
#pragma unroll
  for (int hf = 0; hf < 2; ++hf) {
    __syncthreads();
#pragma unroll
    for (int db = 0; db < 2; ++db) {
      const int adb = hf * 2 + db;
#pragma unroll
      for (int r = 0; r < 16; ++r) {
        const int dl = db * 32 + (r & 3) + 8 * (r >> 2) + 4 * hi;
        Otr[lo * 68 + dl] = accO[adb][r] * invl;
      }
    }
    __syncthreads();
    const int mr = lane >> 1;
    const int c0 = (lane & 1) * 32;
    const float* src2 = Otr + mr * 68 + c0;
    float* dst = Og + obase + (size_t)mr * DIM + hf * 64 + c0;
#pragma unroll
    for (int i = 0; i < 8; ++i)
      *(float4*)(dst + i * 4) = *(const float4*)(src2 + i * 4);
  }
}

// ---------------- fallback (small ws): inline-convert version, (256,3) ----------
__global__ __launch_bounds__(256, 3)
void SeqAttention_inline_kernel(const float* __restrict__ Qg,
                                const float* __restrict__ Kg,
                                const float* __restrict__ Vg,
                                const float* __restrict__ Sg,
                                float* __restrict__ Og) {
  __shared__ __align__(16) unsigned char SM[36864];
  unsigned short* Ks = (unsigned short*)SM;
  unsigned short* Pb = (unsigned short*)SM;
  unsigned short* Vt = (unsigned short*)(SM + 18432);

  const int tid = threadIdx.x;
  const int wid = tid >> 6;
  const int lane = tid & 63;
  const int lo = lane & 31;
  const int hi = lane >> 5;

  const int bi = blockIdx.x;
  const int q = bi >> 8;
  const int h = ((bi & 15) + (q << 2)) & 15;
  const int b = (bi >> 4) & 7;
  const int mt = (((bi >> 7) & 1) << 2) | q;
  const int bh = b * NHEADS + h;
  const int m0 = mt << 7;

  const float sv = Sg[h];
  const float tval = 991.0f - sv * 1024.0f;
  int nf = (int)floorf(tval);
  nf = nf < 0 ? 0 : nf;
  const int tile0 = nf >> 6;

  short8 qf[8];
  {
    const float* qrow = Qg + ((size_t)bh * MQ + m0 + wid * 32 + lo) * DIM + hi * 8;
#pragma unroll
    for (int kc = 0; kc < 8; ++kc) {
      float4 x = *(const float4*)(qrow + kc * 16);
      float4 y = *(const float4*)(qrow + kc * 16 + 4);
      uint4 u;
      u.x = pk2(x.x * QSCALE_L2E, x.y * QSCALE_L2E);
      u.y = pk2(x.z * QSCALE_L2E, x.w * QSCALE_L2E);
      u.z = pk2(y.x * QSCALE_L2E, y.y * QSCALE_L2E);
      u.w = pk2(y.z * QSCALE_L2E, y.w * QSCALE_L2E);
      qf[kc] = __builtin_bit_cast(short8, u);
    }
  }

  f32x16 accO[4] = {};
  float Mrun = -3.0e38f, lrun = 0.0f;
  const float hoff = (float)hi * 0.125f;

  const int vnp2 = (tid >> 3) * 2;
  const int vdq = (tid & 7) * 4;
  const int kn = tid >> 4;
  const int kc0 = (tid & 15) * 8;

  const float* Kbh = Kg + (size_t)bh * LK * DIM;
  const float* Vbh = Vg + (size_t)bh * LK * DIM;

  for (int it = tile0; it < 16; ++it) {
    const int n0 = it << 6;
#pragma unroll
    for (int p = 0; p < 4; ++p) {
      const int n = kn + p * 16;
      const float* kp = Kbh + (size_t)(n0 + n) * DIM + kc0;
      float4 a = *(const float4*)kp;
      float4 bb = *(const float4*)(kp + 4);
      uint4 u;
      u.x = pk2(a.x, a.y); u.y = pk2(a.z, a.w);
      u.z = pk2(bb.x, bb.y); u.w = pk2(bb.z, bb.w);
      *(uint4*)&Ks[n * 136 + kc0] = u;
    }
#pragma unroll
    for (int p = 0; p < 4; ++p) {
      const int d0 = p * 32 + vdq;
      const float* vp = Vbh + (size_t)(n0 + vnp2) * DIM + d0;
      float4 a = *(const float4*)vp;
      float4 bb = *(const float4*)(vp + DIM);
      *(unsigned*)&Vt[(d0 + 0) * 72 + vnp2] = pk2(a.x, bb.x);
      *(unsigned*)&Vt[(d0 + 1) * 72 + vnp2] = pk2(a.y, bb.y);
      *(unsigned*)&Vt[(d0 + 2) * 72 + vnp2] = pk2(a.z, bb.z);
      *(unsigned*)&Vt[(d0 + 3) * 72 + vnp2] = pk2(a.w, bb.w);
    }
    __syncthreads();

    f32x16 sa[2] = {};
#pragma unroll
    for (int kc = 0; kc < 8; ++kc) {
      short8 k0 = ld8(&Ks[lo * 136 + kc * 16 + hi * 8]);
      short8 k1 = ld8(&Ks[(32 + lo) * 136 + kc * 16 + hi * 8]);
      sa[0] = __builtin_amdgcn_mfma_f32_32x32x16_bf16(k0, qf[kc], sa[0], 0, 0, 0);
      sa[1] = __builtin_amdgcn_mfma_f32_32x32x16_bf16(k1, qf[kc], sa[1], 0, 0, 0);
    }
    __syncthreads();

    float rm = -3.0e38f;
#pragma unroll
    for (int r = 0; r < 16; ++r) rm = fmaxf(rm, fmaxf(sa[0][r], sa[1][r]));
    rm = fmaxf(rm, __shfl_xor(rm, 32));
    const float Mn = fmaxf(Mrun, rm);
    const float alpha = __builtin_amdgcn_exp2f(Mrun - Mn);
    Mrun = Mn;

    const bool fullmask = ((float)n0 >= tval + 32.0f);
    const float b0 = ((float)n0 - tval) * 0.03125f + hoff;
    unsigned short* pbrow = Pb + wid * (32 * 72) + lo * 72;
    float rs = 0.0f;
#pragma unroll
    for (int nb = 0; nb < 2; ++nb) {
#pragma unroll
      for (int g = 0; g < 4; ++g) {
        float pv0, pv1, pv2, pv3;
#pragma unroll
        for (int i = 0; i < 4; ++i) {
          float e = __builtin_amdgcn_exp2f(sa[nb][g * 4 + i] - Mn);
          if (!fullmask) {
            float mv = b0 + (float)(i + 8 * g + 32 * nb) * 0.03125f;
            mv = __builtin_amdgcn_fmed3f(mv, 0.0f, 1.0f);
            e *= mv;
          }
          rs += e;
          if (i == 0) pv0 = e; else if (i == 1) pv1 = e; else if (i == 2) pv2 = e; else pv3 = e;
        }
        uint2 w;
        w.x = pk2(pv0, pv1);
        w.y = pk2(pv2, pv3);
        *(uint2*)(pbrow + nb * 32 + g * 8 + hi * 4) = w;
      }
    }
    rs += __shfl_xor(rs, 32);
    lrun = lrun * alpha + rs;
#pragma unroll
    for (int db = 0; db < 4; ++db)
#pragma unroll
      for (int r = 0; r < 16; ++r) accO[db][r] *= alpha;

#pragma unroll
    for (int pc = 0; pc < 4; ++pc) {
      short8 pf = ld8(&Pb[wid * (32 * 72) + lo * 72 + pc * 16 + hi * 8]);
#pragma unroll
      for (int db = 0; db < 4; ++db) {
        short8 vf = ld8(&Vt[(db * 32 + lo) * 72 + pc * 16 + hi * 8]);
        accO[db] = __builtin_amdgcn_mfma_f32_32x32x16_bf16(vf, pf, accO[db], 0, 0, 0);
      }
    }
    __syncthreads();
  }

  const float invl = 1.0f / lrun;
  float* Otr = (float*)SM + wid * (32 * 68);
  const size_t obase = ((size_t)bh * MQ + m0 + wid * 32) * DIM;
#pragma unroll
  for (int hf = 0; hf < 2; ++hf) {
    __syncthreads();
#pragma unroll
    for (int db = 0; db < 2; ++db) {
      const int adb = hf * 2 + db;
#pragma unroll
      for (int r = 0; r < 16; ++r) {
        const int dl = db * 32 + (r & 3) + 8 * (r >> 2) + 4 * hi;
        Otr[lo * 68 + dl] = accO[adb][r] * invl;
      }
    }
    __syncthreads();
    const int mr = lane >> 1;
    const int c0 = (lane & 1) * 32;
    const float* src2 = Otr + mr * 68 + c0;
    float* dst = Og + obase + (size_t)mr * DIM + hf * 64 + c0;
#pragma unroll
    for (int i = 0; i < 8; ++i)
      *(float4*)(dst + i * 4) = *(const float4*)(src2 + i * 4);
  }
}

extern "C" void kernel_launch(void* const* d_in, const int* in_sizes, int n_in,
                              void* d_out, int out_size, void* d_ws, size_t ws_size,
                              hipStream_t stream) {
  const float* Q = (const float*)d_in[0];
  const float* K = (const float*)d_in[1];
  const float* V = (const float*)d_in[2];
  const float* S = (const float*)d_in[3];
  float* O = (float*)d_out;
  if (ws_size >= WS_NEED) {
    SeqAttention_prep_kernel<<<2048, 256, 0, stream>>>(K, V, S, (unsigned char*)d_ws);
    SeqAttention_59579786330678_kernel<<<1024, 256, 0, stream>>>(
        Q, (const unsigned char*)d_ws, S, O);
  } else {
    SeqAttention_inline_kernel<<<1024, 256, 0, stream>>>(Q, K, V, S, O);
  }
}

// Round 5
// 266.504 us; speedup vs baseline: 1.2554x; 1.0727x over previous
//
#include <hip/hip_runtime.h>

#define NHEADS 16
#define DIM 128
#define MQ 1024
#define LK 1024

#define K_BYTES 16384          // 64 rows x 128 ushort, rotate-swizzled 16B chunks
#define V_BYTES 16384          // 128 rows x 64 ushort, rotate-swizzled 16B chunks
#define TILE_BYTES 32768       // K_BYTES + V_BYTES
#define WS_NEED ((size_t)128 * 16 * TILE_BYTES)   // 67,108,864 B

typedef short short8 __attribute__((ext_vector_type(8)));
typedef float f32x16 __attribute__((ext_vector_type(16)));
typedef unsigned u32x4 __attribute__((ext_vector_type(4)));

// (1/sqrt(128)) * log2(e): fold softmax scale + exp2-domain into Q conversion
#define QSCALE_L2E 0.12751722f

// two f32 -> packed 2xbf16, hardware RTNE (1 inst vs 6-inst bit trick)
__device__ __forceinline__ unsigned cvtpk(float a, float b) {
  unsigned r;
  asm("v_cvt_pk_bf16_f32 %0, %1, %2" : "=v"(r) : "v"(a), "v"(b));
  return r;
}
__device__ __forceinline__ short8 ld8(const unsigned short* p) {
  return __builtin_bit_cast(short8, *(const uint4*)p);
}

typedef const __attribute__((address_space(1))) void gvoid_t;
typedef __attribute__((address_space(3))) void lvoid_t;
__device__ __forceinline__ void gl_lds16(const void* g, void* l) {
  __builtin_amdgcn_global_load_lds((gvoid_t*)g, (lvoid_t*)l, 16, 0, 0);
}

// ---------------- prep kernel: fp32 K/V -> rotate-swizzled bf16 K-tile + V^T-tile in ws ----
// Rotation: physical 16B chunk = (logical_chunk + row) mod nchunks. Reproduces exactly the
// +1-chunk-padded layout's bank-group pattern (measured 0 conflicts) at power-of-2 tile size.
// Main kernel stages linearly into LDS and applies the same rotation on reads.
__global__ __launch_bounds__(256)
void SeqAttention_prep_kernel(const float* __restrict__ Kg,
                              const float* __restrict__ Vg,
                              const float* __restrict__ Sg,
                              unsigned char* __restrict__ ws) {
  const int bid = blockIdx.x;           // 2048 = 128 bh x 16 tiles
  const int bh = bid >> 4;
  const int it = bid & 15;
  const float sv = Sg[bh & (NHEADS - 1)];
  const float tval = 991.0f - sv * 1024.0f;
  int nf = (int)floorf(tval);
  nf = nf < 0 ? 0 : nf;
  if (it < (nf >> 6)) return;           // tile fully masked for this head -> never read

  const int tid = threadIdx.x;
  const int n0 = it << 6;
  unsigned char* dst = ws + (size_t)bid * TILE_BYTES;

  // ---- K: direct convert, rotate-swizzled chunk placement ----
  {
    const int kn = tid >> 4;
    const int kcc = tid & 15;           // logical 16B chunk 0..15
    const int kc0 = kcc * 8;            // float col
    const float* Kb = Kg + (size_t)bh * LK * DIM;
    unsigned short* dk = (unsigned short*)dst;
#pragma unroll
    for (int p = 0; p < 4; ++p) {
      const int n = kn + p * 16;
      const float* kp = Kb + (size_t)(n0 + n) * DIM + kc0;
      float4 a = *(const float4*)kp;
      float4 bb = *(const float4*)(kp + 4);
      uint4 u;
      u.x = cvtpk(a.x, a.y); u.y = cvtpk(a.z, a.w);
      u.z = cvtpk(bb.x, bb.y); u.w = cvtpk(bb.z, bb.w);
      *(uint4*)&dk[n * 128 + (((kcc + n) & 15) << 3)] = u;
    }
  }

  // ---- V: transpose via LDS (padded stride 72 internally), rotate-swizzled copy-out ----
  __shared__ __align__(16) unsigned short Vt[128 * 72];
  {
    const int vnp2 = (tid >> 3) * 2;
    const int vdq = (tid & 7) * 4;
    const float* Vb = Vg + (size_t)bh * LK * DIM;
#pragma unroll
    for (int p = 0; p < 4; ++p) {
      const int d0 = p * 32 + vdq;
      const float* vp = Vb + (size_t)(n0 + vnp2) * DIM + d0;
      float4 a = *(const float4*)vp;
      float4 bb = *(const float4*)(vp + DIM);
      *(unsigned*)&Vt[(d0 + 0) * 72 + vnp2] = cvtpk(a.x, bb.x);
      *(unsigned*)&Vt[(d0 + 1) * 72 + vnp2] = cvtpk(a.y, bb.y);
      *(unsigned*)&Vt[(d0 + 2) * 72 + vnp2] = cvtpk(a.z, bb.z);
      *(unsigned*)&Vt[(d0 + 3) * 72 + vnp2] = cvtpk(a.w, bb.w);
    }
  }
  __syncthreads();
  {
    const int d = tid >> 3;
    const int ch = tid & 7;             // logical 16B chunk 0..7
#pragma unroll
    for (int p = 0; p < 4; ++p) {
      const int dd = d + p * 32;
      *(uint4*)(dst + K_BYTES + dd * 128 + (((ch + dd) & 7) << 4)) =
          *(const uint4*)&Vt[dd * 72 + ch * 8];
    }
  }
}

// ---------------- main kernel: static-LPT block order (longest heads dispatched first),
// ---------------- K dbuf + V single-buf, counted vmcnt, in-register P, 48 KB LDS ----------
__global__ __launch_bounds__(256, 3)
void SeqAttention_59579786330678_kernel(const float* __restrict__ Qg,
                                        const unsigned char* __restrict__ ws,
                                        const float* __restrict__ Sg,
                                        float* __restrict__ Og) {
  // LDS: Kbuf0 @0 (16K), Kbuf1 @16K, Vbuf @32K (16K). Total 48K -> 3 blocks/CU.
  // epilogue reuses SM as float Otr[4][32][68] (34816 B)
  __shared__ __align__(16) unsigned char SM[49152];

  const int tid = threadIdx.x;
  const int wid = tid >> 6;   // 0..3
  const int lane = tid & 63;
  const int lo = lane & 31;   // MFMA col -> this lane's query (within wave)
  const int hi = lane >> 5;   // MFMA k-half / row-offset bit
  const float hoff = (float)hi * 0.125f;

  // Static LPT: blockIdx>>6 = head rank by span DESC (longest = most iterations first).
  // HW dispatches roughly in blockIdx order and backfills as blocks retire -> short heads
  // fill the tail. No atomics, no cross-launch state; correctness is order-independent.
  const int bi = blockIdx.x;
  const int rank = bi >> 6;
  int h = 0;
  for (int cand = 0; cand < 16; ++cand) {
    const float c = Sg[cand];
    int rr = 0;
    for (int o = 0; o < 16; ++o) {
      const float ov = Sg[o];
      rr += (ov > c || (ov == c && o < cand)) ? 1 : 0;
    }
    if (rr == rank) h = cand;
  }
  const int b = (bi >> 3) & 7;
  const int mt = bi & 7;
  const int bh = b * NHEADS + h;
  const int m0 = mt << 7;

  const float sv = Sg[h];
  const float tval = 991.0f - sv * 1024.0f;
  int nf = (int)floorf(tval);
  nf = nf < 0 ? 0 : nf;
  const int tile0 = nf >> 6;

  // loop-invariant Q fragments (B-operand of K*Q^T), scale folded into bf16 convert
  short8 qf[8];
  {
    const float* qrow = Qg + ((size_t)bh * MQ + m0 + wid * 32 + lo) * DIM + hi * 8;
#pragma unroll
    for (int kc = 0; kc < 8; ++kc) {
      float4 x = *(const float4*)(qrow + kc * 16);
      float4 y = *(const float4*)(qrow + kc * 16 + 4);
      uint4 u;
      u.x = cvtpk(x.x * QSCALE_L2E, x.y * QSCALE_L2E);
      u.y = cvtpk(x.z * QSCALE_L2E, x.w * QSCALE_L2E);
      u.z = cvtpk(y.x * QSCALE_L2E, y.y * QSCALE_L2E);
      u.w = cvtpk(y.z * QSCALE_L2E, y.w * QSCALE_L2E);
      qf[kc] = __builtin_bit_cast(short8, u);
    }
  }

  f32x16 accO[4] = {};              // O^T accumulator: 4 d-blocks of 32
  float Mrun = -3.0e38f, lrun = 0.0f;

  const unsigned char* wsb = ws + (size_t)bh * 16 * TILE_BYTES;

  // ---- prologue: stage K(tile0) into Kbuf0 ----
  {
    const unsigned char* src = wsb + (size_t)tile0 * TILE_BYTES;
    for (int c = wid; c < 16; c += 4)
      gl_lds16(src + c * 1024 + lane * 16, SM + c * 1024);
  }
  __syncthreads();   // drains vmcnt: Kbuf0 ready

  int cur = 0;
  for (int it = tile0; it < 16; ++it) {
    // V(it) stage: waited at pre-PV barrier (hidden under QK^T+softmax)
    {
      const unsigned char* src = wsb + (size_t)it * TILE_BYTES + K_BYTES;
      for (int c = wid; c < 16; c += 4)
        gl_lds16(src + c * 1024 + lane * 16, SM + 32768 + c * 1024);
    }
    // K(it+1) prefetch: drained at end-of-iter syncthreads
    if (it + 1 < 16) {
      const unsigned char* srcn = wsb + (size_t)(it + 1) * TILE_BYTES;
      unsigned char* dstl = SM + (cur ^ 1) * K_BYTES;
      for (int c = wid; c < 16; c += 4)
        gl_lds16(srcn + c * 1024 + lane * 16, dstl + c * 1024);
    }

    const unsigned short* Ksb = (const unsigned short*)(SM + cur * K_BYTES);
    const unsigned short* Vtb = (const unsigned short*)(SM + 32768);
    const int n0 = it << 6;

    // ---- S^T = K * Q^T (rotate-swizzled reads == padded layout's bank pattern) ----
    f32x16 sa[2] = {};
    __builtin_amdgcn_s_setprio(1);
#pragma unroll
    for (int kc = 0; kc < 8; ++kc) {
      const int kph = ((kc * 2 + hi + lo) & 15) << 3;
      short8 k0 = ld8(&Ksb[lo * 128 + kph]);
      short8 k1 = ld8(&Ksb[(32 + lo) * 128 + kph]);
      sa[0] = __builtin_amdgcn_mfma_f32_32x32x16_bf16(k0, qf[kc], sa[0], 0, 0, 0);
      sa[1] = __builtin_amdgcn_mfma_f32_32x32x16_bf16(k1, qf[kc], sa[1], 0, 0, 0);
    }
    __builtin_amdgcn_s_setprio(0);

    // ---- online softmax (registers), defer-max: skip rescale when growth < 8 (exp2 dom) ----
    float rm = -3.0e38f;
#pragma unroll
    for (int r = 0; r < 16; ++r) rm = fmaxf(rm, fmaxf(sa[0][r], sa[1][r]));
    rm = fmaxf(rm, __shfl_xor(rm, 32));
    if (!__all(rm <= Mrun + 8.0f)) {
      const float Mn = fmaxf(Mrun, rm);
      const float alpha = __builtin_amdgcn_exp2f(Mrun - Mn);
      lrun *= alpha;
#pragma unroll
      for (int db = 0; db < 4; ++db)
#pragma unroll
        for (int r = 0; r < 16; ++r) accO[db][r] *= alpha;
      Mrun = Mn;
    }

    const bool fullmask = ((float)n0 >= tval + 32.0f);
    const float b0 = ((float)n0 - tval) * 0.03125f + hoff;
    float rs = 0.0f;
#pragma unroll
    for (int nb = 0; nb < 2; ++nb) {
#pragma unroll
      for (int g = 0; g < 4; ++g) {
#pragma unroll
        for (int i = 0; i < 4; ++i) {
          float e = __builtin_amdgcn_exp2f(sa[nb][g * 4 + i] - Mrun);
          if (!fullmask) {
            float mv = b0 + (float)(i + 8 * g + 32 * nb) * 0.03125f;
            mv = __builtin_amdgcn_fmed3f(mv, 0.0f, 1.0f);
            e *= mv;
          }
          rs += e;
          sa[nb][g * 4 + i] = e;   // keep P in registers
        }
      }
    }
    rs += __shfl_xor(rs, 32);
    lrun += rs;

    // ---- PV B-fragments in-register: cvt_pk + permlane32_swap ----
    u32x4 pfv[4];
#pragma unroll
    for (int pc = 0; pc < 4; ++pc) {
      const int nb = pc >> 1;
      const int gX = (pc & 1) * 2;
      const int gY = gX + 1;
#pragma unroll
      for (int i0 = 0; i0 < 4; i0 += 2) {
        unsigned X = cvtpk(sa[nb][gX * 4 + i0], sa[nb][gX * 4 + i0 + 1]);
        unsigned Y = cvtpk(sa[nb][gY * 4 + i0], sa[nb][gY * 4 + i0 + 1]);
        asm("v_permlane32_swap_b32 %0, %1" : "+v"(X), "+v"(Y));
        pfv[pc][i0 >> 1] = X;
        pfv[pc][2 + (i0 >> 1)] = Y;
      }
    }

    // ---- wait V(it) staged; keep the 4 K-prefetch loads in flight ----
    if (it + 1 < 16) {
      asm volatile("s_waitcnt vmcnt(4)" ::: "memory");
    } else {
      asm volatile("s_waitcnt vmcnt(0)" ::: "memory");
    }
    __builtin_amdgcn_s_barrier();
    __builtin_amdgcn_sched_barrier(0);   // keep Vtb reads below the barrier

    // ---- O^T += V^T * P^T ----
    __builtin_amdgcn_s_setprio(1);
#pragma unroll
    for (int pc = 0; pc < 4; ++pc) {
      short8 pf = __builtin_bit_cast(short8, pfv[pc]);
#pragma unroll
      for (int db = 0; db < 4; ++db) {
        const int vph = ((pc * 2 + hi + lo) & 7) << 3;
        short8 vf = ld8(&Vtb[(db * 32 + lo) * 64 + vph]);
        accO[db] = __builtin_amdgcn_mfma_f32_32x32x16_bf16(vf, pf, accO[db], 0, 0, 0);
      }
    }
    __builtin_amdgcn_s_setprio(0);

    __syncthreads();   // drains K(it+1); protects Vbuf + Kbuf[cur] for restage
    cur ^= 1;
  }

  // ---- epilogue: /l, transpose O^T -> O via LDS (two d-halves), coalesced stores ----
  const float invl = 1.0f / lrun;
  float* Otr = (float*)SM + wid * (32 * 68);
  const size_t obase = ((size_t)bh * MQ + m0 + wid * 32) * DIM;
#pragma unroll
  for (int hf = 0; hf < 2; ++hf) {
    __syncthreads();
#pragma unroll
    for (int db = 0; db < 2; ++db) {
      const int adb = hf * 2 + db;
#pragma unroll
      for (int r = 0; r < 16; ++r) {
        const int dl = db * 32 + (r & 3) + 8 * (r >> 2) + 4 * hi;
        Otr[lo * 68 + dl] = accO[adb][r] * invl;
      }
    }
    __syncthreads();
    const int mr = lane >> 1;
    const int c0 = (lane & 1) * 32;
    const float* src2 = Otr + mr * 68 + c0;
    float* dst = Og + obase + (size_t)mr * DIM + hf * 64 + c0;
#pragma unroll
    for (int i = 0; i < 8; ++i)
      *(float4*)(dst + i * 4) = *(const float4*)(src2 + i * 4);
  }
}

// ---------------- fallback (small ws): inline-convert version, (256,3) ----------
__global__ __launch_bounds__(256, 3)
void SeqAttention_inline_kernel(const float* __restrict__ Qg,
                                const float* __restrict__ Kg,
                                const float* __restrict__ Vg,
                                const float* __restrict__ Sg,
                                float* __restrict__ Og) {
  __shared__ __align__(16) unsigned char SM[36864];
  unsigned short* Ks = (unsigned short*)SM;
  unsigned short* Pb = (unsigned short*)SM;
  unsigned short* Vt = (unsigned short*)(SM + 18432);

  const int tid = threadIdx.x;
  const int wid = tid >> 6;
  const int lane = tid & 63;
  const int lo = lane & 31;
  const int hi = lane >> 5;

  const int bi = blockIdx.x;
  const int q = bi >> 8;
  const int h = ((bi & 15) + (q << 2)) & 15;
  const int b = (bi >> 4) & 7;
  const int mt = (((bi >> 7) & 1) << 2) | q;
  const int bh = b * NHEADS + h;
  const int m0 = mt << 7;

  const float sv = Sg[h];
  const float tval = 991.0f - sv * 1024.0f;
  int nf = (int)floorf(tval);
  nf = nf < 0 ? 0 : nf;
  const int tile0 = nf >> 6;

  short8 qf[8];
  {
    const float* qrow = Qg + ((size_t)bh * MQ + m0 + wid * 32 + lo) * DIM + hi * 8;
#pragma unroll
    for (int kc = 0; kc < 8; ++kc) {
      float4 x = *(const float4*)(qrow + kc * 16);
      float4 y = *(const float4*)(qrow + kc * 16 + 4);
      uint4 u;
      u.x = cvtpk(x.x * QSCALE_L2E, x.y * QSCALE_L2E);
      u.y = cvtpk(x.z * QSCALE_L2E, x.w * QSCALE_L2E);
      u.z = cvtpk(y.x * QSCALE_L2E, y.y * QSCALE_L2E);
      u.w = cvtpk(y.z * QSCALE_L2E, y.w * QSCALE_L2E);
      qf[kc] = __builtin_bit_cast(short8, u);
    }
  }

  f32x16 accO[4] = {};
  float Mrun = -3.0e38f, lrun = 0.0f;
  const float hoff = (float)hi * 0.125f;

  const int vnp2 = (tid >> 3) * 2;
  const int vdq = (tid & 7) * 4;
  const int kn = tid >> 4;
  const int kc0 = (tid & 15) * 8;

  const float* Kbh = Kg + (size_t)bh * LK * DIM;
  const float* Vbh = Vg + (size_t)bh * LK * DIM;

  for (int it = tile0; it < 16; ++it) {
    const int n0 = it << 6;
#pragma unroll
    for (int p = 0; p < 4; ++p) {
      const int n = kn + p * 16;
      const float* kp = Kbh + (size_t)(n0 + n) * DIM + kc0;
      float4 a = *(const float4*)kp;
      float4 bb = *(const float4*)(kp + 4);
      uint4 u;
      u.x = cvtpk(a.x, a.y); u.y = cvtpk(a.z, a.w);
      u.z = cvtpk(bb.x, bb.y); u.w = cvtpk(bb.z, bb.w);
      *(uint4*)&Ks[n * 136 + kc0] = u;
    }
#pragma unroll
    for (int p = 0; p < 4; ++p) {
      const int d0 = p * 32 + vdq;
      const float* vp = Vbh + (size_t)(n0 + vnp2) * DIM + d0;
      float4 a = *(const float4*)vp;
      float4 bb = *(const float4*)(vp + DIM);
      *(unsigned*)&Vt[(d0 + 0) * 72 + vnp2] = cvtpk(a.x, bb.x);
      *(unsigned*)&Vt[(d0 + 1) * 72 + vnp2] = cvtpk(a.y, bb.y);
      *(unsigned*)&Vt[(d0 + 2) * 72 + vnp2] = cvtpk(a.z, bb.z);
      *(unsigned*)&Vt[(d0 + 3) * 72 + vnp2] = cvtpk(a.w, bb.w);
    }
    __syncthreads();

    f32x16 sa[2] = {};
#pragma unroll
    for (int kc = 0; kc < 8; ++kc) {
      short8 k0 = ld8(&Ks[lo * 136 + kc * 16 + hi * 8]);
      short8 k1 = ld8(&Ks[(32 + lo) * 136 + kc * 16 + hi * 8]);
      sa[0] = __builtin_amdgcn_mfma_f32_32x32x16_bf16(k0, qf[kc], sa[0], 0, 0, 0);
      sa[1] = __builtin_amdgcn_mfma_f32_32x32x16_bf16(k1, qf[kc], sa[1], 0, 0, 0);
    }
    __syncthreads();

    float rm = -3.0e38f;
#pragma unroll
    for (int r = 0; r < 16; ++r) rm = fmaxf(rm, fmaxf(sa[0][r], sa[1][r]));
    rm = fmaxf(rm, __shfl_xor(rm, 32));
    const float Mn = fmaxf(Mrun, rm);
    const float alpha = __builtin_amdgcn_exp2f(Mrun - Mn);
    Mrun = Mn;

    const bool fullmask = ((float)n0 >= tval + 32.0f);
    const float b0 = ((float)n0 - tval) * 0.03125f + hoff;
    unsigned short* pbrow = Pb + wid * (32 * 72) + lo * 72;
    float rs = 0.0f;
#pragma unroll
    for (int nb = 0; nb < 2; ++nb) {
#pragma unroll
      for (int g = 0; g < 4; ++g) {
        float pv0, pv1, pv2, pv3;
#pragma unroll
        for (int i = 0; i < 4; ++i) {
          float e = __builtin_amdgcn_exp2f(sa[nb][g * 4 + i] - Mn);
          if (!fullmask) {
            float mv = b0 + (float)(i + 8 * g + 32 * nb) * 0.03125f;
            mv = __builtin_amdgcn_fmed3f(mv, 0.0f, 1.0f);
            e *= mv;
          }
          rs += e;
          if (i == 0) pv0 = e; else if (i == 1) pv1 = e; else if (i == 2) pv2 = e; else pv3 = e;
        }
        uint2 w;
        w.x = cvtpk(pv0, pv1);
        w.y = cvtpk(pv2, pv3);
        *(uint2*)(pbrow + nb * 32 + g * 8 + hi * 4) = w;
      }
    }
    rs += __shfl_xor(rs, 32);
    lrun = lrun * alpha + rs;
#pragma unroll
    for (int db = 0; db < 4; ++db)
#pragma unroll
      for (int r = 0; r < 16; ++r) accO[db][r] *= alpha;

#pragma unroll
    for (int pc = 0; pc < 4; ++pc) {
      short8 pf = ld8(&Pb[wid * (32 * 72) + lo * 72 + pc * 16 + hi * 8]);
#pragma unroll
      for (int db = 0; db < 4; ++db) {
        short8 vf = ld8(&Vt[(db * 32 + lo) * 72 + pc * 16 + hi * 8]);
        accO[db] = __builtin_amdgcn_mfma_f32_32x32x16_bf16(vf, pf, accO[db], 0, 0, 0);
      }
    }
    __syncthreads();
  }

  const float invl = 1.0f / lrun;
  float* Otr = (float*)SM + wid * (32 * 68);
  const size_t obase = ((size_t)bh * MQ + m0 + wid * 32) * DIM;
#pragma unroll
  for (int hf = 0; hf < 2; ++hf) {
    __syncthreads();
#pragma unroll
    for (int db = 0; db < 2; ++db) {
      const int adb = hf * 2 + db;
#pragma unroll
      for (int r = 0; r < 16; ++r) {
        const int dl = db * 32 + (r & 3) + 8 * (r >> 2) + 4 * hi;
        Otr[lo * 68 + dl] = accO[adb][r] * invl;
      }
    }
    __syncthreads();
    const int mr = lane >> 1;
    const int c0 = (lane & 1) * 32;
    const float* src2 = Otr + mr * 68 + c0;
    float* dst = Og + obase + (size_t)mr * DIM + hf * 64 + c0;
#pragma unroll
    for (int i = 0; i < 8; ++i)
      *(float4*)(dst + i * 4) = *(const float4*)(src2 + i * 4);
  }
}

extern "C" void kernel_launch(void* const* d_in, const int* in_sizes, int n_in,
                              void* d_out, int out_size, void* d_ws, size_t ws_size,
                              hipStream_t stream) {
  const float* Q = (const float*)d_in[0];
  const float* K = (const float*)d_in[1];
  const float* V = (const float*)d_in[2];
  const float* S = (const float*)d_in[3];
  float* O = (float*)d_out;
  if (ws_size >= WS_NEED) {
    SeqAttention_prep_kernel<<<2048, 256, 0, stream>>>(K, V, S, (unsigned char*)d_ws);
    SeqAttention_59579786330678_kernel<<<1024, 256, 0, stream>>>(
        Q, (const unsigned char*)d_ws, S, O);
  } else {
    SeqAttention_inline_kernel<<<1024, 256, 0, stream>>>(Q, K, V, S, O);
  }
}